// Round 3
// baseline (49.734 us; speedup 1.0000x reference)
//
#include <hip/hip_runtime.h>

// out = cos(in), except out[:,1] = cos(in[:,0]) * cos(in[:,1]).
// Row length = 16 floats, so elems 0 and 1 of each row are in the same float4:
// quad k of a row, k = i & 3; fixup applies only when k == 0 (r.y *= r.x).
// Purely memory-bound: 128 MiB in + 128 MiB out, roofline ~43 us @ 6.3 TB/s.
// R1: timed 45.6 us = 5.9 TB/s (93% of achievable). R2: non-temporal builtins
// need native clang vectors, not HIP_vector_type — use ext_vector_type(4).

typedef float f32x4 __attribute__((ext_vector_type(4)));

__global__ __launch_bounds__(256) void qae_cos_kernel(
    const f32x4* __restrict__ in, f32x4* __restrict__ out, int nquads) {
    int idx = blockIdx.x * blockDim.x + threadIdx.x;
    int stride = gridDim.x * blockDim.x;
    for (int i = idx; i < nquads; i += stride) {
        f32x4 v = __builtin_nontemporal_load(&in[i]);
        f32x4 r;
        r.x = __cosf(v.x);
        r.y = __cosf(v.y);
        r.z = __cosf(v.z);
        r.w = __cosf(v.w);
        // first quad of each 16-float row: out.y = cos(x0)*cos(x1)
        if ((i & 3) == 0) r.y *= r.x;
        __builtin_nontemporal_store(r, &out[i]);
    }
}

extern "C" void kernel_launch(void* const* d_in, const int* in_sizes, int n_in,
                              void* d_out, int out_size, void* d_ws, size_t ws_size,
                              hipStream_t stream) {
    const f32x4* in = (const f32x4*)d_in[0];
    f32x4* out = (f32x4*)d_out;
    int nquads = in_sizes[0] / 4;  // 8,388,608 quads

    const int block = 256;
    int grid = 2048;  // grid-stride: ~16 quads/thread; 8 blocks/CU = full occupancy
    qae_cos_kernel<<<grid, block, 0, stream>>>(in, out, nquads);
}

// Round 4
// 45.367 us; speedup vs baseline: 1.0963x; 1.0963x over previous
//
#include <hip/hip_runtime.h>

// out = cos(in), except out[:,1] = cos(in[:,0]) * cos(in[:,1]).
// Row length = 16 floats, so elems 0 and 1 of each row are in the same float4:
// quad k of a row, k = i & 3; fixup applies only when k == 0 (r.y *= r.x).
// Purely memory-bound: 128 MiB in + 128 MiB out. Measured mixed-stream
// ceiling (float4 D2D copy, m13) = 6.29 TB/s -> ideal ~42.7 us.
// R1: this kernel = 45.6 us = 5.89 TB/s = 93.6% of copy ceiling.
// R3: non-temporal load/store REGRESSED (49.7 us) — nt loads lose L2/L3
// burst aggregation; write-allocate costs nothing (fill kernel = 7 TB/s
// with normal stores). Reverted to the R1 version.

__global__ __launch_bounds__(256) void qae_cos_kernel(
    const float4* __restrict__ in, float4* __restrict__ out, int nquads) {
    int idx = blockIdx.x * blockDim.x + threadIdx.x;
    int stride = gridDim.x * blockDim.x;
    for (int i = idx; i < nquads; i += stride) {
        float4 v = in[i];
        float4 r;
        r.x = __cosf(v.x);
        r.y = __cosf(v.y);
        r.z = __cosf(v.z);
        r.w = __cosf(v.w);
        // first quad of each 16-float row: out.y = cos(x0)*cos(x1)
        if ((i & 3) == 0) r.y *= r.x;
        out[i] = r;
    }
}

extern "C" void kernel_launch(void* const* d_in, const int* in_sizes, int n_in,
                              void* d_out, int out_size, void* d_ws, size_t ws_size,
                              hipStream_t stream) {
    const float4* in = (const float4*)d_in[0];
    float4* out = (float4*)d_out;
    int nquads = in_sizes[0] / 4;  // 8,388,608 quads

    const int block = 256;
    int grid = 2048;  // grid-stride: ~16 quads/thread; 8 blocks/CU = full occupancy
    qae_cos_kernel<<<grid, block, 0, stream>>>(in, out, nquads);
}